// Round 17
// baseline (24.360 us; speedup 1.0000x reference)
//
#include <hip/hip_runtime.h>

#define Bt 32768
#define Dt 64
#define St 16
#define Ht 128
#define At 17

typedef __attribute__((ext_vector_type(8))) short bf16x8;
typedef __attribute__((ext_vector_type(4))) float f32x4;

__device__ __forceinline__ unsigned short f2bf(float f) {
  union { float f; unsigned u; } v; v.f = f;
  unsigned r = v.u + 0x7FFFu + ((v.u >> 16) & 1u);  // RNE
  return (unsigned short)(r >> 16);
}

// packed f32x2 -> bf16x2 in one VALU op (gfx950 v_cvt_pk_bf16_f32)
__device__ __forceinline__ unsigned cvtpk(float a, float b) {
  unsigned r;
  asm("v_cvt_pk_bf16_f32 %0, %1, %2" : "=v"(r) : "v"(a), "v"(b));
  return r;
}

// tanh(acc + bias) with b2 = 2*bias precomputed
__device__ __forceinline__ float tanh_fb(float acc, float b2) {
  const float t = __expf(__builtin_fmaf(acc, 2.0f, b2));  // inf-safe
  const float r = __builtin_amdgcn_rcpf(t + 1.0f);
  return __builtin_fmaf(-2.0f, r, 1.0f);
}

__device__ __forceinline__ f32x4 MFMA(bf16x8 a, bf16x8 b, f32x4 c) {
  return __builtin_amdgcn_mfma_f32_16x16x32_bf16(a, b, c, 0, 0, 0);
}

#define LGKM0() asm volatile("s_waitcnt lgkmcnt(0)" ::: "memory")

__device__ __forceinline__ bf16x8 wrd(const char* base, int srw, int n, int c,
                                      int lg, int msw) {
  return *(const bf16x8*)(base + n * srw + (((c) + lg * 16) ^ msw));
}

// store tanh(acc)+bias with b2 pre-doubled, in registers
__device__ __forceinline__ void storeh(char* hw, int msw, int lg, int t,
                                       const f32x4 acc, const f32x4 b2) {
  const unsigned lo = cvtpk(tanh_fb(acc[0], b2[0]), tanh_fb(acc[1], b2[1]));
  const unsigned hi = cvtpk(tanh_fb(acc[2], b2[2]), tanh_fb(acc[3], b2[3]));
  *(unsigned long long*)(hw + ((32 * t + 8 * lg) ^ msw)) =
      (unsigned long long)lo | ((unsigned long long)hi << 32);
}

// ---- one 64-row tile, actor role (biases in registers) ----
__device__ __forceinline__ void tile_actor(
    int tbase, int rnext, bool dopref, int& rowcur,
    f32x4& cx0, f32x4& cx1, f32x4& cx2, f32x4& cx3,
    const char* wbuf, char* hw, const float* obs,
    const f32x4 (&b1d)[8], const f32x4 (&b2d)[8], const f32x4 ba3v,
    const float ba316, float* out,
    int m, int lg, int msw, int wm, int cs) {
  union { bf16x8 v; unsigned u[4]; } XB0, XB1;
  XB0.u[0] = cvtpk(cx0[0], cx0[1]); XB0.u[1] = cvtpk(cx0[2], cx0[3]);
  XB0.u[2] = cvtpk(cx1[0], cx1[1]); XB0.u[3] = cvtpk(cx1[2], cx1[3]);
  XB1.u[0] = cvtpk(cx2[0], cx2[1]); XB1.u[1] = cvtpk(cx2[2], cx2[3]);
  XB1.u[2] = cvtpk(cx3[0], cx3[1]); XB1.u[3] = cvtpk(cx3[2], cx3[3]);
  const int myrow = rowcur;
  if (dopref) {  // next tile's obs: in flight across this tile's compute
    const float* ap = obs + rnext * Dt + lg * 8;
    cx0 = *(const f32x4*)(ap);      cx1 = *(const f32x4*)(ap + 4);
    cx2 = *(const f32x4*)(ap + 32); cx3 = *(const f32x4*)(ap + 36);
  }
  rowcur = rnext;
#pragma unroll
  for (int nt = 0; nt < 8; ++nt) {
    const bf16x8 a0 = wrd(wbuf, 128, nt * 16 + m, 0, lg, msw);
    const bf16x8 a1 = wrd(wbuf, 128, nt * 16 + m, 64, lg, msw);
    f32x4 acc = {0.f, 0.f, 0.f, 0.f};
    acc = MFMA(a0, XB0.v, acc);
    acc = MFMA(a1, XB1.v, acc);
    storeh(hw, msw, lg, nt, acc, b1d[nt]);
  }
  LGKM0();
  const bf16x8 h0 = *(const bf16x8*)(hw + ((0   + 16 * lg) ^ msw));
  const bf16x8 h1 = *(const bf16x8*)(hw + ((64  + 16 * lg) ^ msw));
  const bf16x8 h2 = *(const bf16x8*)(hw + ((128 + 16 * lg) ^ msw));
  const bf16x8 h3 = *(const bf16x8*)(hw + ((192 + 16 * lg) ^ msw));
#pragma unroll
  for (int nt = 0; nt < 8; ++nt) {
    const int n = nt * 16 + m;
    const bf16x8 w0 = wrd(wbuf + 16384, 256, n, 0, lg, msw);
    const bf16x8 w1 = wrd(wbuf + 16384, 256, n, 64, lg, msw);
    const bf16x8 w2 = wrd(wbuf + 16384, 256, n, 128, lg, msw);
    const bf16x8 w3 = wrd(wbuf + 16384, 256, n, 192, lg, msw);
    f32x4 acc = {0.f, 0.f, 0.f, 0.f};
    acc = MFMA(w0, h0, acc); acc = MFMA(w1, h1, acc);
    acc = MFMA(w2, h2, acc); acc = MFMA(w3, h3, acc);
    storeh(hw, msw, lg, nt, acc, b2d[nt]);
  }
  LGKM0();
  const bf16x8 H0 = *(const bf16x8*)(hw + ((0   + 16 * lg) ^ msw));
  const bf16x8 H1 = *(const bf16x8*)(hw + ((64  + 16 * lg) ^ msw));
  const bf16x8 H2 = *(const bf16x8*)(hw + ((128 + 16 * lg) ^ msw));
  const bf16x8 H3 = *(const bf16x8*)(hw + ((192 + 16 * lg) ^ msw));
  const char* W3 = wbuf + 49152;
  const bf16x8 e0 = wrd(W3, 256, m, 0, lg, msw);
  const bf16x8 e1 = wrd(W3, 256, m, 64, lg, msw);
  const bf16x8 e2 = wrd(W3, 256, m, 128, lg, msw);
  const bf16x8 e3 = wrd(W3, 256, m, 192, lg, msw);
  const bf16x8 f0 = wrd(W3, 256, 16 + m, 0, lg, msw);
  const bf16x8 f1 = wrd(W3, 256, 16 + m, 64, lg, msw);
  const bf16x8 f2 = wrd(W3, 256, 16 + m, 128, lg, msw);
  const bf16x8 f3 = wrd(W3, 256, 16 + m, 192, lg, msw);
  f32x4 p0 = {0.f, 0.f, 0.f, 0.f}, p1 = {0.f, 0.f, 0.f, 0.f};
  p0 = MFMA(e0, H0, p0); p0 = MFMA(e1, H1, p0);
  p0 = MFMA(e2, H2, p0); p0 = MFMA(e3, H3, p0);
  p1 = MFMA(f0, H0, p1); p1 = MFMA(f1, H1, p1);
  p1 = MFMA(f2, H2, p1); p1 = MFMA(f3, H3, p1);
  if (tbase + wm < cs) {
    float* orow = out + myrow * At;
#pragma unroll
    for (int i = 0; i < 4; ++i)                 // n = 4lg+i in 0..15
      orow[4 * lg + i] = p0[i] + ba3v[i];
    if (lg == 0) orow[16] = p1[0] + ba316;      // n = 16
  }
}

// ---- one 64-row tile, critic role (biases/Wc3 in registers) ----
__device__ __forceinline__ void tile_critic(
    int tbase, int rnext, bool dopref, int& rowcur,
    f32x4& cx0, f32x4& cx1, f32x4& cx2, f32x4& cx3,
    const char* wbuf, char* hw, const float* obs,
    const f32x4 (&b1d)[8], const f32x4 (&b2d)[8], const f32x4 (&wv)[8],
    const float bc3s, float* out,
    int m, int lg, int msw, int wm, int cs, int lane) {
  union { bf16x8 v; unsigned u[4]; } XB0, XB1;
  XB0.u[0] = cvtpk(cx0[0], cx0[1]); XB0.u[1] = cvtpk(cx0[2], cx0[3]);
  XB0.u[2] = cvtpk(cx1[0], cx1[1]); XB0.u[3] = cvtpk(cx1[2], cx1[3]);
  XB1.u[0] = cvtpk(cx2[0], cx2[1]); XB1.u[1] = cvtpk(cx2[2], cx2[3]);
  XB1.u[2] = cvtpk(cx3[0], cx3[1]); XB1.u[3] = cvtpk(cx3[2], cx3[3]);
  const int myrow = rowcur;
  if (dopref) {
    const float* ap = obs + rnext * Dt + lg * 8;
    cx0 = *(const f32x4*)(ap);      cx1 = *(const f32x4*)(ap + 4);
    cx2 = *(const f32x4*)(ap + 32); cx3 = *(const f32x4*)(ap + 36);
  }
  rowcur = rnext;
#pragma unroll
  for (int nt = 0; nt < 8; ++nt) {
    const bf16x8 a0 = wrd(wbuf, 128, nt * 16 + m, 0, lg, msw);
    const bf16x8 a1 = wrd(wbuf, 128, nt * 16 + m, 64, lg, msw);
    f32x4 acc = {0.f, 0.f, 0.f, 0.f};
    acc = MFMA(a0, XB0.v, acc);
    acc = MFMA(a1, XB1.v, acc);
    storeh(hw, msw, lg, nt, acc, b1d[nt]);
  }
  LGKM0();
  const bf16x8 h0 = *(const bf16x8*)(hw + ((0   + 16 * lg) ^ msw));
  const bf16x8 h1 = *(const bf16x8*)(hw + ((64  + 16 * lg) ^ msw));
  const bf16x8 h2 = *(const bf16x8*)(hw + ((128 + 16 * lg) ^ msw));
  const bf16x8 h3 = *(const bf16x8*)(hw + ((192 + 16 * lg) ^ msw));
  float vp = 0.f;
#pragma unroll
  for (int nt = 0; nt < 8; ++nt) {
    const int n = nt * 16 + m;
    const bf16x8 w0 = wrd(wbuf + 16384, 256, n, 0, lg, msw);
    const bf16x8 w1 = wrd(wbuf + 16384, 256, n, 64, lg, msw);
    const bf16x8 w2 = wrd(wbuf + 16384, 256, n, 128, lg, msw);
    const bf16x8 w3 = wrd(wbuf + 16384, 256, n, 192, lg, msw);
    f32x4 acc = {0.f, 0.f, 0.f, 0.f};
    acc = MFMA(w0, h0, acc); acc = MFMA(w1, h1, acc);
    acc = MFMA(w2, h2, acc); acc = MFMA(w3, h3, acc);
#pragma unroll
    for (int i = 0; i < 4; ++i)
      vp = __builtin_fmaf(tanh_fb(acc[i], b2d[nt][i]), wv[nt][i], vp);
  }
  vp += __shfl_xor(vp, 16);
  vp += __shfl_xor(vp, 32);
  if (lane < 16 && (tbase + wm < cs)) out[Bt * At + myrow] = vp + bc3s;
}

// ---------- SINGLE dispatch: in-block compact + fp32->LDS weight convert + MLP ----------
// block (role, s, idx): owns rows b in [idx*2048,(idx+1)*2048) with sid[b]==s.
// Partition is exact (each row in exactly one block per role); no workspace needed.
// Waves whose whole 16-row set lies past cs skip the tile entirely (no block-wide
// syncs inside tile bodies; hbuf rows are wave-private; wbuf read-only).
__global__ __launch_bounds__(256, 2) void k_all(
    const float* __restrict__ obs, const int* __restrict__ sid,
    const float* __restrict__ Wa1, const float* __restrict__ ba1,
    const float* __restrict__ Wa2, const float* __restrict__ ba2,
    const float* __restrict__ Wa3, const float* __restrict__ ba3,
    const float* __restrict__ Wc1, const float* __restrict__ bc1,
    const float* __restrict__ Wc2, const float* __restrict__ bc2,
    const float* __restrict__ Wc3, const float* __restrict__ bc3,
    float* __restrict__ out) {
  __shared__ __align__(16) char wbuf[57344];   // L1@0 16K | L2@16K 32K | L3@48K 8K
  __shared__ __align__(16) char hbuf[16384];   // 64 rows x 256B activations
  __shared__ unsigned short rlist[2048];       // compacted row ids (worst case)
  __shared__ int rcnt;

  const int tid = threadIdx.x;
  const int wave = tid >> 6, lane = tid & 63;
  const int m = lane & 15, lg = lane >> 4;
  const bool actor = (blockIdx.x == 0);
  const int s = blockIdx.y, idx = blockIdx.z;
  const int wm = wave * 16 + m;
  const int wfirst = wave * 16;

  if (tid == 0) rcnt = 0;
  __syncthreads();

  // ---- ballot-compact rows of skill s from this block's sid slice ----
  const int ebase = idx * 2048;
#pragma unroll
  for (int r = 0; r < 8; ++r) {
    const int e = ebase + r * 256 + tid;
    const bool p = (sid[e] == s);
    const unsigned long long mk = __ballot(p);
    int wb = 0;
    if (lane == 0) wb = atomicAdd(&rcnt, (int)__popcll(mk));
    wb = __shfl(wb, 0);
    if (p) rlist[wb + (int)__popcll(mk & ((1ULL << lane) - 1ULL))] =
        (unsigned short)e;
  }
  __syncthreads();                       // rlist/rcnt ready
  const int cs = rcnt;
  const int cm1 = (cs > 0) ? cs - 1 : 0;
  const int ntl = (cs + 63) >> 6;

  // ---- tile-0 obs gather issued early (hides under weight conversion) ----
  f32x4 cx0 = {}, cx1 = {}, cx2 = {}, cx3 = {};
  int rowcur = 0;
  if (cs > 0) {
    rowcur = rlist[min(wm, cm1)];
    const float* ap = obs + rowcur * Dt + lg * 8;
    cx0 = *(const f32x4*)(ap);      cx1 = *(const f32x4*)(ap + 4);
    cx2 = *(const f32x4*)(ap + 32); cx3 = *(const f32x4*)(ap + 36);
  }

  // ---- convert this (role,s)'s fp32 weights -> bf16 [n][k] swizzled LDS image ----
  {
    const float* W1s = (actor ? Wa1 : Wc1) + s * Dt * Ht;  // [k=64][n=128]
    const float* W2s = (actor ? Wa2 : Wc2) + s * Ht * Ht;  // [k=128][n=128]
#pragma unroll
    for (int i = 0; i < 16; ++i) {     // L1 image: 4096 u32 (SRW=128)
      const int w = i * 256 + tid;
      const int n = w & 127, kp = w >> 7;
      const unsigned u =
          cvtpk(W1s[(2 * kp) * Ht + n], W1s[(2 * kp + 1) * Ht + n]);
      *(unsigned*)(wbuf + n * 128 + ((4 * kp) ^ ((n & 7) << 4))) = u;
    }
#pragma unroll
    for (int i = 0; i < 32; ++i) {     // L2 image: 8192 u32 (SRW=256)
      const int w = i * 256 + tid;
      const int n = w & 127, kp = w >> 7;
      const unsigned u =
          cvtpk(W2s[(2 * kp) * Ht + n], W2s[(2 * kp + 1) * Ht + n]);
      *(unsigned*)(wbuf + 16384 + n * 256 + ((4 * kp) ^ ((n & 7) << 4))) = u;
    }
    if (actor) {                       // L3 image: rows n<17 only (rest discarded)
      const float* W3s = Wa3 + s * Ht * At;
      for (int e = tid; e < Ht * At; e += 256) {
        const int k = e / At, n = e - k * At;
        *(unsigned short*)(wbuf + 49152 + n * 256 +
                           ((2 * k) ^ ((n & 7) << 4))) = f2bf(W3s[e]);
      }
    }
  }

  char* hw = hbuf + wm * 256;
  const int msw = (m & 7) << 4;

  if (actor) {
    // preload biases into registers (pre-doubled) BEFORE the barrier
    f32x4 b1d[8], b2d[8];
#pragma unroll
    for (int nt = 0; nt < 8; ++nt) {
      const f32x4 t1 = *(const f32x4*)(ba1 + s * Ht + nt * 16 + lg * 4);
      const f32x4 t2 = *(const f32x4*)(ba2 + s * Ht + nt * 16 + lg * 4);
      b1d[nt] = t1 + t1;
      b2d[nt] = t2 + t2;
    }
    const f32x4 ba3v = *(const f32x4*)(ba3 + s * At + 4 * lg);
    const float ba316 = ba3[s * At + 16];
    __syncthreads();                   // wbuf image + preloads complete
    for (int t = 0; t < ntl; ++t) {
      if (t * 64 + wfirst >= cs) break;   // wave-level tail skip
      const int rn = rlist[min((t + 1) * 64 + wm, cm1)];
      tile_actor(t * 64, rn, t + 1 < ntl, rowcur, cx0, cx1, cx2, cx3,
                 wbuf, hw, obs, b1d, b2d, ba3v, ba316, out, m, lg, msw, wm, cs);
    }
  } else {
    f32x4 b1d[8], b2d[8], wv[8];
#pragma unroll
    for (int nt = 0; nt < 8; ++nt) {
      const f32x4 t1 = *(const f32x4*)(bc1 + s * Ht + nt * 16 + lg * 4);
      const f32x4 t2 = *(const f32x4*)(bc2 + s * Ht + nt * 16 + lg * 4);
      wv[nt] = *(const f32x4*)(Wc3 + s * Ht + nt * 16 + lg * 4);
      b1d[nt] = t1 + t1;
      b2d[nt] = t2 + t2;
    }
    const float bc3s = bc3[s];
    __syncthreads();
    for (int t = 0; t < ntl; ++t) {
      if (t * 64 + wfirst >= cs) break;   // wave-level tail skip
      const int rn = rlist[min((t + 1) * 64 + wm, cm1)];
      tile_critic(t * 64, rn, t + 1 < ntl, rowcur, cx0, cx1, cx2, cx3,
                  wbuf, hw, obs, b1d, b2d, wv, bc3s, out, m, lg, msw, wm, cs,
                  lane);
    }
  }
}

extern "C" void kernel_launch(void* const* d_in, const int* in_sizes, int n_in,
                              void* d_out, int out_size, void* d_ws, size_t ws_size,
                              hipStream_t stream) {
  const float* obs = (const float*)d_in[0];
  const int* sid   = (const int*)d_in[1];
  const float* Wa1 = (const float*)d_in[2];
  const float* ba1 = (const float*)d_in[3];
  const float* Wa2 = (const float*)d_in[4];
  const float* ba2 = (const float*)d_in[5];
  const float* Wa3 = (const float*)d_in[6];
  const float* ba3 = (const float*)d_in[7];
  const float* Wc1 = (const float*)d_in[8];
  const float* bc1 = (const float*)d_in[9];
  const float* Wc2 = (const float*)d_in[10];
  const float* bc2 = (const float*)d_in[11];
  const float* Wc3 = (const float*)d_in[12];
  const float* bc3 = (const float*)d_in[13];
  float* out = (float*)d_out;

  k_all<<<dim3(2, 16, 16), dim3(256), 0, stream>>>(
      obs, sid, Wa1, ba1, Wa2, ba2, Wa3, ba3, Wc1, bc1, Wc2, bc2, Wc3, bc3,
      out);
}

// Round 18
// 24.052 us; speedup vs baseline: 1.0128x; 1.0128x over previous
//
#include <hip/hip_runtime.h>

#define Bt 32768
#define Dt 64
#define St 16
#define Ht 128
#define At 17

typedef __attribute__((ext_vector_type(8))) short bf16x8;
typedef __attribute__((ext_vector_type(4))) float f32x4;

__device__ __forceinline__ unsigned short f2bf(float f) {
  union { float f; unsigned u; } v; v.f = f;
  unsigned r = v.u + 0x7FFFu + ((v.u >> 16) & 1u);  // RNE
  return (unsigned short)(r >> 16);
}

// packed f32x2 -> bf16x2 in one VALU op (gfx950 v_cvt_pk_bf16_f32)
__device__ __forceinline__ unsigned cvtpk(float a, float b) {
  unsigned r;
  asm("v_cvt_pk_bf16_f32 %0, %1, %2" : "=v"(r) : "v"(a), "v"(b));
  return r;
}

// tanh(acc + bias) with b2 = 2*bias precomputed
__device__ __forceinline__ float tanh_fb(float acc, float b2) {
  const float t = __expf(__builtin_fmaf(acc, 2.0f, b2));  // inf-safe
  const float r = __builtin_amdgcn_rcpf(t + 1.0f);
  return __builtin_fmaf(-2.0f, r, 1.0f);
}

__device__ __forceinline__ f32x4 MFMA(bf16x8 a, bf16x8 b, f32x4 c) {
  return __builtin_amdgcn_mfma_f32_16x16x32_bf16(a, b, c, 0, 0, 0);
}

#define LGKM0() asm volatile("s_waitcnt lgkmcnt(0)" ::: "memory")

__device__ __forceinline__ bf16x8 wrd(const char* base, int srw, int n, int c,
                                      int lg, int msw) {
  return *(const bf16x8*)(base + n * srw + (((c) + lg * 16) ^ msw));
}

// store tanh(acc)+bias with b2 pre-doubled, in registers
__device__ __forceinline__ void storeh(char* hw, int msw, int lg, int t,
                                       const f32x4 acc, const f32x4 b2) {
  const unsigned lo = cvtpk(tanh_fb(acc[0], b2[0]), tanh_fb(acc[1], b2[1]));
  const unsigned hi = cvtpk(tanh_fb(acc[2], b2[2]), tanh_fb(acc[3], b2[3]));
  *(unsigned long long*)(hw + ((32 * t + 8 * lg) ^ msw)) =
      (unsigned long long)lo | ((unsigned long long)hi << 32);
}

// ---- one 64-row tile, actor role (biases in registers) ----
__device__ __forceinline__ void tile_actor(
    int tbase, int rnext, bool dopref, int& rowcur,
    f32x4& cx0, f32x4& cx1, f32x4& cx2, f32x4& cx3,
    const char* wbuf, char* hw, const float* obs,
    const f32x4 (&b1d)[8], const f32x4 (&b2d)[8], const f32x4 ba3v,
    const float ba316, float* out,
    int m, int lg, int msw, int wm, int cs) {
  union { bf16x8 v; unsigned u[4]; } XB0, XB1;
  XB0.u[0] = cvtpk(cx0[0], cx0[1]); XB0.u[1] = cvtpk(cx0[2], cx0[3]);
  XB0.u[2] = cvtpk(cx1[0], cx1[1]); XB0.u[3] = cvtpk(cx1[2], cx1[3]);
  XB1.u[0] = cvtpk(cx2[0], cx2[1]); XB1.u[1] = cvtpk(cx2[2], cx2[3]);
  XB1.u[2] = cvtpk(cx3[0], cx3[1]); XB1.u[3] = cvtpk(cx3[2], cx3[3]);
  const int myrow = rowcur;
  if (dopref) {  // next tile's obs: in flight across this tile's compute
    const float* ap = obs + rnext * Dt + lg * 8;
    cx0 = *(const f32x4*)(ap);      cx1 = *(const f32x4*)(ap + 4);
    cx2 = *(const f32x4*)(ap + 32); cx3 = *(const f32x4*)(ap + 36);
  }
  rowcur = rnext;
#pragma unroll
  for (int nt = 0; nt < 8; ++nt) {
    const bf16x8 a0 = wrd(wbuf, 128, nt * 16 + m, 0, lg, msw);
    const bf16x8 a1 = wrd(wbuf, 128, nt * 16 + m, 64, lg, msw);
    f32x4 acc = {0.f, 0.f, 0.f, 0.f};
    acc = MFMA(a0, XB0.v, acc);
    acc = MFMA(a1, XB1.v, acc);
    storeh(hw, msw, lg, nt, acc, b1d[nt]);
  }
  LGKM0();
  const bf16x8 h0 = *(const bf16x8*)(hw + ((0   + 16 * lg) ^ msw));
  const bf16x8 h1 = *(const bf16x8*)(hw + ((64  + 16 * lg) ^ msw));
  const bf16x8 h2 = *(const bf16x8*)(hw + ((128 + 16 * lg) ^ msw));
  const bf16x8 h3 = *(const bf16x8*)(hw + ((192 + 16 * lg) ^ msw));
#pragma unroll
  for (int nt = 0; nt < 8; ++nt) {
    const int n = nt * 16 + m;
    const bf16x8 w0 = wrd(wbuf + 16384, 256, n, 0, lg, msw);
    const bf16x8 w1 = wrd(wbuf + 16384, 256, n, 64, lg, msw);
    const bf16x8 w2 = wrd(wbuf + 16384, 256, n, 128, lg, msw);
    const bf16x8 w3 = wrd(wbuf + 16384, 256, n, 192, lg, msw);
    f32x4 acc = {0.f, 0.f, 0.f, 0.f};
    acc = MFMA(w0, h0, acc); acc = MFMA(w1, h1, acc);
    acc = MFMA(w2, h2, acc); acc = MFMA(w3, h3, acc);
    storeh(hw, msw, lg, nt, acc, b2d[nt]);
  }
  LGKM0();
  const bf16x8 H0 = *(const bf16x8*)(hw + ((0   + 16 * lg) ^ msw));
  const bf16x8 H1 = *(const bf16x8*)(hw + ((64  + 16 * lg) ^ msw));
  const bf16x8 H2 = *(const bf16x8*)(hw + ((128 + 16 * lg) ^ msw));
  const bf16x8 H3 = *(const bf16x8*)(hw + ((192 + 16 * lg) ^ msw));
  const char* W3 = wbuf + 49152;
  const bf16x8 e0 = wrd(W3, 256, m, 0, lg, msw);
  const bf16x8 e1 = wrd(W3, 256, m, 64, lg, msw);
  const bf16x8 e2 = wrd(W3, 256, m, 128, lg, msw);
  const bf16x8 e3 = wrd(W3, 256, m, 192, lg, msw);
  const bf16x8 f0 = wrd(W3, 256, 16 + m, 0, lg, msw);
  const bf16x8 f1 = wrd(W3, 256, 16 + m, 64, lg, msw);
  const bf16x8 f2 = wrd(W3, 256, 16 + m, 128, lg, msw);
  const bf16x8 f3 = wrd(W3, 256, 16 + m, 192, lg, msw);
  f32x4 p0 = {0.f, 0.f, 0.f, 0.f}, p1 = {0.f, 0.f, 0.f, 0.f};
  p0 = MFMA(e0, H0, p0); p0 = MFMA(e1, H1, p0);
  p0 = MFMA(e2, H2, p0); p0 = MFMA(e3, H3, p0);
  p1 = MFMA(f0, H0, p1); p1 = MFMA(f1, H1, p1);
  p1 = MFMA(f2, H2, p1); p1 = MFMA(f3, H3, p1);
  if (tbase + wm < cs) {
    float* orow = out + myrow * At;
#pragma unroll
    for (int i = 0; i < 4; ++i)                 // n = 4lg+i in 0..15
      orow[4 * lg + i] = p0[i] + ba3v[i];
    if (lg == 0) orow[16] = p1[0] + ba316;      // n = 16
  }
}

// ---- one 64-row tile, critic role (biases/Wc3 in registers) ----
__device__ __forceinline__ void tile_critic(
    int tbase, int rnext, bool dopref, int& rowcur,
    f32x4& cx0, f32x4& cx1, f32x4& cx2, f32x4& cx3,
    const char* wbuf, char* hw, const float* obs,
    const f32x4 (&b1d)[8], const f32x4 (&b2d)[8], const f32x4 (&wv)[8],
    const float bc3s, float* out,
    int m, int lg, int msw, int wm, int cs, int lane) {
  union { bf16x8 v; unsigned u[4]; } XB0, XB1;
  XB0.u[0] = cvtpk(cx0[0], cx0[1]); XB0.u[1] = cvtpk(cx0[2], cx0[3]);
  XB0.u[2] = cvtpk(cx1[0], cx1[1]); XB0.u[3] = cvtpk(cx1[2], cx1[3]);
  XB1.u[0] = cvtpk(cx2[0], cx2[1]); XB1.u[1] = cvtpk(cx2[2], cx2[3]);
  XB1.u[2] = cvtpk(cx3[0], cx3[1]); XB1.u[3] = cvtpk(cx3[2], cx3[3]);
  const int myrow = rowcur;
  if (dopref) {
    const float* ap = obs + rnext * Dt + lg * 8;
    cx0 = *(const f32x4*)(ap);      cx1 = *(const f32x4*)(ap + 4);
    cx2 = *(const f32x4*)(ap + 32); cx3 = *(const f32x4*)(ap + 36);
  }
  rowcur = rnext;
#pragma unroll
  for (int nt = 0; nt < 8; ++nt) {
    const bf16x8 a0 = wrd(wbuf, 128, nt * 16 + m, 0, lg, msw);
    const bf16x8 a1 = wrd(wbuf, 128, nt * 16 + m, 64, lg, msw);
    f32x4 acc = {0.f, 0.f, 0.f, 0.f};
    acc = MFMA(a0, XB0.v, acc);
    acc = MFMA(a1, XB1.v, acc);
    storeh(hw, msw, lg, nt, acc, b1d[nt]);
  }
  LGKM0();
  const bf16x8 h0 = *(const bf16x8*)(hw + ((0   + 16 * lg) ^ msw));
  const bf16x8 h1 = *(const bf16x8*)(hw + ((64  + 16 * lg) ^ msw));
  const bf16x8 h2 = *(const bf16x8*)(hw + ((128 + 16 * lg) ^ msw));
  const bf16x8 h3 = *(const bf16x8*)(hw + ((192 + 16 * lg) ^ msw));
  float vp = 0.f;
#pragma unroll
  for (int nt = 0; nt < 8; ++nt) {
    const int n = nt * 16 + m;
    const bf16x8 w0 = wrd(wbuf + 16384, 256, n, 0, lg, msw);
    const bf16x8 w1 = wrd(wbuf + 16384, 256, n, 64, lg, msw);
    const bf16x8 w2 = wrd(wbuf + 16384, 256, n, 128, lg, msw);
    const bf16x8 w3 = wrd(wbuf + 16384, 256, n, 192, lg, msw);
    f32x4 acc = {0.f, 0.f, 0.f, 0.f};
    acc = MFMA(w0, h0, acc); acc = MFMA(w1, h1, acc);
    acc = MFMA(w2, h2, acc); acc = MFMA(w3, h3, acc);
#pragma unroll
    for (int i = 0; i < 4; ++i)
      vp = __builtin_fmaf(tanh_fb(acc[i], b2d[nt][i]), wv[nt][i], vp);
  }
  vp += __shfl_xor(vp, 16);
  vp += __shfl_xor(vp, 32);
  if (lane < 16 && (tbase + wm < cs)) out[Bt * At + myrow] = vp + bc3s;
}

// ---------- SINGLE dispatch: in-block compact + fp32->LDS weight convert + MLP ----------
// block (role, s, idx): owns rows b in [idx*2048,(idx+1)*2048) with sid[b]==s.
// Partition is exact (each row in exactly one block per role); no workspace needed.
__global__ __launch_bounds__(256, 2) void k_all(
    const float* __restrict__ obs, const int* __restrict__ sid,
    const float* __restrict__ Wa1, const float* __restrict__ ba1,
    const float* __restrict__ Wa2, const float* __restrict__ ba2,
    const float* __restrict__ Wa3, const float* __restrict__ ba3,
    const float* __restrict__ Wc1, const float* __restrict__ bc1,
    const float* __restrict__ Wc2, const float* __restrict__ bc2,
    const float* __restrict__ Wc3, const float* __restrict__ bc3,
    float* __restrict__ out) {
  __shared__ __align__(16) char wbuf[57344];   // L1@0 16K | L2@16K 32K | L3@48K 8K
  __shared__ __align__(16) char hbuf[16384];   // 64 rows x 256B activations
  __shared__ unsigned short rlist[2048];       // compacted row ids (worst case)
  __shared__ int rcnt;

  const int tid = threadIdx.x;
  const int wave = tid >> 6, lane = tid & 63;
  const int m = lane & 15, lg = lane >> 4;
  const bool actor = (blockIdx.x == 0);
  const int s = blockIdx.y, idx = blockIdx.z;
  const int wm = wave * 16 + m;

  if (tid == 0) rcnt = 0;
  __syncthreads();

  // ---- ballot-compact rows of skill s from this block's sid slice ----
  const int ebase = idx * 2048;
#pragma unroll
  for (int r = 0; r < 8; ++r) {
    const int e = ebase + r * 256 + tid;
    const bool p = (sid[e] == s);
    const unsigned long long mk = __ballot(p);
    int wb = 0;
    if (lane == 0) wb = atomicAdd(&rcnt, (int)__popcll(mk));
    wb = __shfl(wb, 0);
    if (p) rlist[wb + (int)__popcll(mk & ((1ULL << lane) - 1ULL))] =
        (unsigned short)e;
  }
  __syncthreads();                       // rlist/rcnt ready
  const int cs = rcnt;
  const int cm1 = (cs > 0) ? cs - 1 : 0;
  const int ntl = (cs + 63) >> 6;

  // ---- tile-0 obs gather issued early (hides under weight conversion) ----
  f32x4 cx0 = {}, cx1 = {}, cx2 = {}, cx3 = {};
  int rowcur = 0;
  if (cs > 0) {
    rowcur = rlist[min(wm, cm1)];
    const float* ap = obs + rowcur * Dt + lg * 8;
    cx0 = *(const f32x4*)(ap);      cx1 = *(const f32x4*)(ap + 4);
    cx2 = *(const f32x4*)(ap + 32); cx3 = *(const f32x4*)(ap + 36);
  }

  // ---- convert this (role,s)'s fp32 weights -> bf16 [n][k] swizzled LDS image ----
  {
    const float* W1s = (actor ? Wa1 : Wc1) + s * Dt * Ht;  // [k=64][n=128]
    const float* W2s = (actor ? Wa2 : Wc2) + s * Ht * Ht;  // [k=128][n=128]
#pragma unroll
    for (int i = 0; i < 16; ++i) {     // L1 image: 4096 u32 (SRW=128)
      const int w = i * 256 + tid;
      const int n = w & 127, kp = w >> 7;
      const unsigned u =
          cvtpk(W1s[(2 * kp) * Ht + n], W1s[(2 * kp + 1) * Ht + n]);
      *(unsigned*)(wbuf + n * 128 + ((4 * kp) ^ ((n & 7) << 4))) = u;
    }
#pragma unroll
    for (int i = 0; i < 32; ++i) {     // L2 image: 8192 u32 (SRW=256)
      const int w = i * 256 + tid;
      const int n = w & 127, kp = w >> 7;
      const unsigned u =
          cvtpk(W2s[(2 * kp) * Ht + n], W2s[(2 * kp + 1) * Ht + n]);
      *(unsigned*)(wbuf + 16384 + n * 256 + ((4 * kp) ^ ((n & 7) << 4))) = u;
    }
    if (actor) {                       // L3 image: rows n<17 only (rest discarded)
      const float* W3s = Wa3 + s * Ht * At;
      for (int e = tid; e < Ht * At; e += 256) {
        const int k = e / At, n = e - k * At;
        *(unsigned short*)(wbuf + 49152 + n * 256 +
                           ((2 * k) ^ ((n & 7) << 4))) = f2bf(W3s[e]);
      }
    }
  }

  char* hw = hbuf + wm * 256;
  const int msw = (m & 7) << 4;

  if (actor) {
    // preload biases into registers (pre-doubled) BEFORE the barrier
    f32x4 b1d[8], b2d[8];
#pragma unroll
    for (int nt = 0; nt < 8; ++nt) {
      const f32x4 t1 = *(const f32x4*)(ba1 + s * Ht + nt * 16 + lg * 4);
      const f32x4 t2 = *(const f32x4*)(ba2 + s * Ht + nt * 16 + lg * 4);
      b1d[nt] = t1 + t1;
      b2d[nt] = t2 + t2;
    }
    const f32x4 ba3v = *(const f32x4*)(ba3 + s * At + 4 * lg);
    const float ba316 = ba3[s * At + 16];
    __syncthreads();                   // wbuf image + preloads complete
    for (int t = 0; t < ntl; ++t) {
      const int rn = rlist[min((t + 1) * 64 + wm, cm1)];
      tile_actor(t * 64, rn, t + 1 < ntl, rowcur, cx0, cx1, cx2, cx3,
                 wbuf, hw, obs, b1d, b2d, ba3v, ba316, out, m, lg, msw, wm, cs);
    }
  } else {
    f32x4 b1d[8], b2d[8], wv[8];
#pragma unroll
    for (int nt = 0; nt < 8; ++nt) {
      const f32x4 t1 = *(const f32x4*)(bc1 + s * Ht + nt * 16 + lg * 4);
      const f32x4 t2 = *(const f32x4*)(bc2 + s * Ht + nt * 16 + lg * 4);
      wv[nt] = *(const f32x4*)(Wc3 + s * Ht + nt * 16 + lg * 4);
      b1d[nt] = t1 + t1;
      b2d[nt] = t2 + t2;
    }
    const float bc3s = bc3[s];
    __syncthreads();
    for (int t = 0; t < ntl; ++t) {
      const int rn = rlist[min((t + 1) * 64 + wm, cm1)];
      tile_critic(t * 64, rn, t + 1 < ntl, rowcur, cx0, cx1, cx2, cx3,
                  wbuf, hw, obs, b1d, b2d, wv, bc3s, out, m, lg, msw, wm, cs,
                  lane);
    }
  }
}

extern "C" void kernel_launch(void* const* d_in, const int* in_sizes, int n_in,
                              void* d_out, int out_size, void* d_ws, size_t ws_size,
                              hipStream_t stream) {
  const float* obs = (const float*)d_in[0];
  const int* sid   = (const int*)d_in[1];
  const float* Wa1 = (const float*)d_in[2];
  const float* ba1 = (const float*)d_in[3];
  const float* Wa2 = (const float*)d_in[4];
  const float* ba2 = (const float*)d_in[5];
  const float* Wa3 = (const float*)d_in[6];
  const float* ba3 = (const float*)d_in[7];
  const float* Wc1 = (const float*)d_in[8];
  const float* bc1 = (const float*)d_in[9];
  const float* Wc2 = (const float*)d_in[10];
  const float* bc2 = (const float*)d_in[11];
  const float* Wc3 = (const float*)d_in[12];
  const float* bc3 = (const float*)d_in[13];
  float* out = (float*)d_out;

  k_all<<<dim3(2, 16, 16), dim3(256), 0, stream>>>(
      obs, sid, Wa1, ba1, Wa2, ba2, Wa3, ba3, Wc1, bc1, Wc2, bc2, Wc3, bc3,
      out);
}